// Round 3
// baseline (172.244 us; speedup 1.0000x reference)
//
#include <hip/hip_runtime.h>
#include <math.h>

// Problem constants (fixed by setup_inputs): N src points, M targets, D=3.
constexpr int N_SRC = 16384;
constexpr int M_TAR = 16384;

// R3: one main kernel. 512 blocks x 1024 threads (16 waves) = 2 blocks/CU,
// all co-resident. Block owns 32 targets, covers ALL sources:
//   wave wv (0..15) covers sources [wv*1024, wv*1024+1024)
//   half-wave slice s (lane>>5) covers 512 of those
//   each lane: 1 target (lane&31), 512 sources as 128 iters x 4 interleaved
//   chains (j = base + i*4 + c) -> 4 loads/iter share one voffset, imm offs.
// Inner loop tracks min of v with loop-counter i embedded in the low 7
// mantissa bits (pure v_min_f32, no cmp/cndmask). Loss recomputed exactly
// from the winning index, so embedding only perturbs near-tie argmin picks.
constexpr int BLOCKS = M_TAR / 32;   // 512
constexpr int TPB = 1024;            // 16 waves
constexpr int WAVES = 16;

constexpr size_t W_BYTES = (size_t)N_SRC * 16;

// w[j] = (-2sx,-2sy,-2sz,||s||^2): argmin_j d2 == argmin_j (w.tx+w.ty+w.tz+w.w)
__global__ void prep3(const float* __restrict__ src, float4* __restrict__ w,
                      float* __restrict__ out) {
    int j = blockIdx.x * 256 + threadIdx.x;
    if (j == 0) out[0] = 0.0f;  // d_out poisoned 0xAA before every launch
    float sx = src[3 * j + 0], sy = src[3 * j + 1], sz = src[3 * j + 2];
    w[j] = make_float4(-2.0f * sx, -2.0f * sy, -2.0f * sz,
                       sx * sx + sy * sy + sz * sz);
}

__device__ __forceinline__ float embed_idx(float v, unsigned i) {
    return __uint_as_float((__float_as_uint(v) & 0xFFFFFF80u) | i);
}

__global__ __launch_bounds__(TPB, 8) void nn4(const float* __restrict__ tar,
                                              const float4* __restrict__ w,
                                              const float* __restrict__ src,
                                              float* __restrict__ out) {
    const int tid   = threadIdx.x;
    const int lane  = tid & 63;
    const int wv    = __builtin_amdgcn_readfirstlane(tid >> 6);  // 0..15
    const int tl    = lane & 31;   // target within block
    const int slice = lane >> 5;   // 0/1: which 512-source half this lane scans
    const int t     = blockIdx.x * 32 + tl;

    const float tx = tar[3 * t + 0];
    const float ty = tar[3 * t + 1];
    const float tz = tar[3 * t + 2];

    const float4* wp = w + wv * 1024;   // wave-uniform base -> saddr loads
    int off = slice * 512;              // per-lane element offset

    float b0 = INFINITY, b1 = INFINITY, b2 = INFINITY, b3 = INFINITY;

#pragma unroll 2
    for (unsigned i = 0; i < 128; ++i) {
        float4 a = wp[off + 0];
        float4 b = wp[off + 1];
        float4 c = wp[off + 2];
        float4 d = wp[off + 3];
        float v0 = fmaf(a.x, tx, fmaf(a.y, ty, fmaf(a.z, tz, a.w)));
        float v1 = fmaf(b.x, tx, fmaf(b.y, ty, fmaf(b.z, tz, b.w)));
        float v2 = fmaf(c.x, tx, fmaf(c.y, ty, fmaf(c.z, tz, c.w)));
        float v3 = fmaf(d.x, tx, fmaf(d.y, ty, fmaf(d.z, tz, d.w)));
        b0 = fminf(b0, embed_idx(v0, i));
        b1 = fminf(b1, embed_idx(v1, i));
        b2 = fminf(b2, embed_idx(v2, i));
        b3 = fminf(b3, embed_idx(v3, i));
        off += 4;
    }

    // chain merge (values still carry embedded i; compare as floats)
    float bv = b0; int bc = 0;
    if (b1 < bv) { bv = b1; bc = 1; }
    if (b2 < bv) { bv = b2; bc = 2; }
    if (b3 < bv) { bv = b3; bc = 3; }
    int bi = (int)(__float_as_uint(bv) & 0x7Fu);
    int j  = wv * 1024 + slice * 512 + bi * 4 + bc;
    float v = __uint_as_float(__float_as_uint(bv) & 0xFFFFFF80u);  // clean

    // slice merge (xor lane 32): both halves end up with the min
    float vv = __shfl_xor(v, 32, 64);
    int   jj = __shfl_xor(j, 32, 64);
    if (vv < v) { v = vv; j = jj; }

    __shared__ float lv[WAVES][32];
    __shared__ int   lj[WAVES][32];
    if (slice == 0) { lv[wv][tl] = v; lj[wv][tl] = j; }
    __syncthreads();

    if (tid < 32) {
        float best = lv[0][tid];
        int   bj   = lj[0][tid];
#pragma unroll
        for (int k = 1; k < WAVES; ++k) {
            float x = lv[k][tid];
            int   y = lj[k][tid];
            if (x < best) { best = x; bj = y; }
        }
        int tt = blockIdx.x * 32 + tid;
        // exact loss term from the winning index (matches reference formula)
        float dx = src[3 * bj + 0] - tar[3 * tt + 0];
        float dy = src[3 * bj + 1] - tar[3 * tt + 1];
        float dz = src[3 * bj + 2] - tar[3 * tt + 2];
        float term = 0.5f * fmaf(dx, dx, fmaf(dy, dy, dz * dz));
#pragma unroll
        for (int o = 16; o > 0; o >>= 1)
            term += __shfl_down(term, o, 32);
        if (tid == 0) atomicAdd(out, term);
    }
}

// ---------------- fallback (ws too small for w): direct distances ----------------
__global__ void zero_out_kernel(float* __restrict__ out) {
    if (threadIdx.x == 0 && blockIdx.x == 0) out[0] = 0.0f;
}

__global__ __launch_bounds__(256) void nn_direct(const float* __restrict__ src,
                                                 const float* __restrict__ tar,
                                                 float* __restrict__ out) {
    const int tid  = threadIdx.x;
    const int lane = tid & 63;
    const int q    = __builtin_amdgcn_readfirstlane(tid >> 6);
    const int t    = blockIdx.x * 64 + lane;
    const float tx = tar[3 * t + 0], ty = tar[3 * t + 1], tz = tar[3 * t + 2];
    const int QUARTER = N_SRC / 4;
    const int j0 = q * QUARTER, j1 = j0 + QUARTER;
    float best = INFINITY;
    int   bi   = j0;
#pragma unroll 4
    for (int j = j0; j < j1; ++j) {
        float sx = src[3 * j + 0], sy = src[3 * j + 1], sz = src[3 * j + 2];
        float dx = sx - tx, dy = sy - ty, dz = sz - tz;
        float v = fmaf(dx, dx, fmaf(dy, dy, dz * dz));
        if (v < best) { best = v; bi = j; }
    }
    __shared__ float sv[4][64];
    __shared__ int   si[4][64];
    sv[q][lane] = best; si[q][lane] = bi;
    __syncthreads();
    if (tid < 64) {
        float bv = sv[0][lane]; int b = si[0][lane];
#pragma unroll
        for (int k = 1; k < 4; ++k) {
            float v = sv[k][lane]; int i = si[k][lane];
            if (v < bv) { bv = v; b = i; }
        }
        float dx = src[3 * b + 0] - tx, dy = src[3 * b + 1] - ty, dz = src[3 * b + 2] - tz;
        float term = 0.5f * fmaf(dx, dx, fmaf(dy, dy, dz * dz));
#pragma unroll
        for (int off = 32; off > 0; off >>= 1) term += __shfl_down(term, off, 64);
        if (lane == 0) atomicAdd(out, term);
    }
}

extern "C" void kernel_launch(void* const* d_in, const int* in_sizes, int n_in,
                              void* d_out, int out_size, void* d_ws, size_t ws_size,
                              hipStream_t stream) {
    const float* src = (const float*)d_in[0];  // src_V [N,3] fp32
    const float* tar = (const float*)d_in[1];  // tar_V [M,3] fp32
    float* out = (float*)d_out;                // scalar loss fp32

    if (ws_size >= W_BYTES) {
        float4* w = (float4*)d_ws;
        prep3<<<N_SRC / 256, 256, 0, stream>>>(src, w, out);
        nn4<<<BLOCKS, TPB, 0, stream>>>(tar, w, src, out);
    } else {
        zero_out_kernel<<<1, 64, 0, stream>>>(out);
        nn_direct<<<M_TAR / 64, 256, 0, stream>>>(src, tar, out);
    }
}

// Round 4
// 89.453 us; speedup vs baseline: 1.9255x; 1.9255x over previous
//
#include <hip/hip_runtime.h>
#include <math.h>

// Problem constants (fixed by setup_inputs): N src points, M targets, D=3.
constexpr int N_SRC = 16384;
constexpr int M_TAR = 16384;

// R4: sources broadcast from LDS (never per-lane VMEM — R3's 64x data-return
// amplification was the regression). 512 blocks x 1024 threads (16 waves,
// 64 KB LDS -> 2 blocks/CU = 32 waves/CU). Block owns 32 targets; thread owns
// 8 targets in registers and scans 64 sources (chunk = tid>>2, j = i*256+chunk
// so each wave's 16 distinct ds addresses are 256 contiguous bytes ->
// conflict-free broadcast). One ds_read_b128 feeds 8 pairs; per pair:
// 3 all-VGPR FMA + mantissa-embed(6-bit i) + v_min_f32 = 5 VALU ops.
constexpr int BLOCKS = M_TAR / 32;     // 512
constexpr int TPB = 1024;              // 16 waves
constexpr int CHUNKS = 256;            // tid>>2
constexpr int TILE = 4096;             // sources per LDS tile (64 KB float4)
constexpr int TILES = N_SRC / TILE;    // 4
constexpr int IT_PER_TILE = TILE / CHUNKS;  // 16 (global i = 0..63, 6 bits)

__global__ void zero_out(float* __restrict__ out) {
    if (threadIdx.x == 0) out[0] = 0.0f;  // d_out poisoned 0xAA each launch
}

__global__ __launch_bounds__(TPB, 8) void nn5(const float* __restrict__ src,
                                              const float* __restrict__ tar,
                                              float* __restrict__ out) {
    __shared__ float4 tile[TILE];  // 64 KB; reused as (fv, fj) in the tail

    const int tid   = threadIdx.x;
    const int chunk = tid >> 2;    // 0..255 : this thread's source subsequence
    const int g     = tid & 3;
    const int tbase = blockIdx.x * 32;

    // 8 targets per thread: local ids g, g+4, ..., g+28. Premultiply by -2 so
    // the inner product folds ||s||^2 into the first FMA (no add, no SGPRs).
    float txm2[8], tym2[8], tzm2[8], best[8];
#pragma unroll
    for (int k = 0; k < 8; ++k) {
        int T = tbase + g + 4 * k;
        txm2[k] = -2.0f * tar[3 * T + 0];
        tym2[k] = -2.0f * tar[3 * T + 1];
        tzm2[k] = -2.0f * tar[3 * T + 2];
        best[k] = INFINITY;
    }

    unsigned idx = 0;  // global iteration i (0..63) embedded in low 6 bits
    for (int tl = 0; tl < TILES; ++tl) {
        // ---- stage tile: 4096 sources as (x,y,z,||s||^2), coalesced reads
#pragma unroll
        for (int k2 = 0; k2 < TILE / TPB; ++k2) {
            int p  = tid + k2 * TPB;
            int j3 = 3 * (tl * TILE + p);
            float x = src[j3 + 0], y = src[j3 + 1], z = src[j3 + 2];
            tile[p] = make_float4(x, y, z, fmaf(x, x, fmaf(y, y, z * z)));
        }
        __syncthreads();

        // ---- scan: v(j) = ||s||^2 - 2 t.s  (argmin-equivalent to d2)
#pragma unroll 4
        for (int il = 0; il < IT_PER_TILE; ++il) {
            float4 s = tile[il * CHUNKS + chunk];
#pragma unroll
            for (int k = 0; k < 8; ++k) {
                float t = fmaf(s.x, txm2[k], s.w);
                t = fmaf(s.y, tym2[k], t);
                t = fmaf(s.z, tzm2[k], t);
                // embed i in low 6 mantissa bits -> pure v_min tracking
                t = __uint_as_float((__float_as_uint(t) & 0xFFFFFFC0u) | idx);
                best[k] = fminf(best[k], t);
            }
            ++idx;
        }
        __syncthreads();
    }

    // ---- tail: resolve indices, merge 256 chunks per target, loss, atomic
    float* fv = (float*)tile;            // [32][256] values  (32 KB)
    int*   fj = (int*)tile + 32 * 256;   // [32][256] indices (32 KB)
#pragma unroll
    for (int k = 0; k < 8; ++k) {
        unsigned b = __float_as_uint(best[k]);
        int j  = (int)((b & 63u) * CHUNKS + chunk);  // j = i*256 + chunk
        int lt = g + 4 * k;
        fv[lt * CHUNKS + chunk] = __uint_as_float(b & 0xFFFFFFC0u);
        fj[lt * CHUNKS + chunk] = j;
    }
    __syncthreads();

    const int tprime = tid >> 5;   // 0..31: target this half-wave reduces
    const int sub    = tid & 31;
    float bv = fv[tprime * CHUNKS + sub];
    int   bj = fj[tprime * CHUNKS + sub];
#pragma unroll
    for (int m = 1; m < 8; ++m) {
        float v = fv[tprime * CHUNKS + sub + 32 * m];
        int   j = fj[tprime * CHUNKS + sub + 32 * m];
        if (v < bv) { bv = v; bj = j; }
    }
#pragma unroll
    for (int s = 16; s >= 1; s >>= 1) {   // xor<32 stays in the half-wave
        float vv = __shfl_xor(bv, s, 64);
        int   jj = __shfl_xor(bj, s, 64);
        if (vv < bv) { bv = vv; bj = jj; }
    }
    __syncthreads();  // done reading fv/fj; safe to reuse

    if (sub == 0) {
        int tt = tbase + tprime;
        // exact loss term from the winning index (reference formula)
        float dx = src[3 * bj + 0] - tar[3 * tt + 0];
        float dy = src[3 * bj + 1] - tar[3 * tt + 1];
        float dz = src[3 * bj + 2] - tar[3 * tt + 2];
        fv[tprime] = 0.5f * fmaf(dx, dx, fmaf(dy, dy, dz * dz));
    }
    __syncthreads();
    if (tid == 0) {
        float ssum = 0.0f;
#pragma unroll
        for (int i = 0; i < 32; ++i) ssum += fv[i];
        atomicAdd(out, ssum);  // device-scope, cross-XCD safe
    }
}

extern "C" void kernel_launch(void* const* d_in, const int* in_sizes, int n_in,
                              void* d_out, int out_size, void* d_ws, size_t ws_size,
                              hipStream_t stream) {
    const float* src = (const float*)d_in[0];  // src_V [N,3] fp32
    const float* tar = (const float*)d_in[1];  // tar_V [M,3] fp32
    float* out = (float*)d_out;                // scalar loss fp32
    (void)d_ws; (void)ws_size;

    zero_out<<<1, 64, 0, stream>>>(out);
    nn5<<<BLOCKS, TPB, 0, stream>>>(src, tar, out);
}

// Round 5
// 87.078 us; speedup vs baseline: 1.9780x; 1.0273x over previous
//
#include <hip/hip_runtime.h>
#include <math.h>

// Problem constants (fixed by setup_inputs): N src points, M targets, D=3.
constexpr int N_SRC = 16384;
constexpr int M_TAR = 16384;

// R5: R4 structure (LDS-broadcast sources; never per-lane VMEM for the
// broadcast stream) with an instruction-exact inner loop:
//   per pair: 3 v_fma_f32 + 1 v_and_or_b32 + 0.5 v_min3_f32  = 4.5 VALU ops
// 512 blocks x 1024 threads (16 waves, 64 KB LDS -> 2 blocks/CU = 8 waves/
// SIMD). Block owns 32 targets; thread owns 8 targets (g = tid&3, stride 4)
// and scans 64 sources: j = row*256 + chunk, row = global i in [0,64),
// chunk = tid>>2. Row index embedded in low 6 mantissa bits via
// v_and_or_b32 (mask in VGPR, uniform row in the one allowed SGPR slot ->
// SALU-materialized, zero VALU cost). Two candidates fold into best via one
// v_min3_f32. Loss recomputed exactly from the winning index afterwards.
constexpr int BLOCKS = M_TAR / 32;   // 512
constexpr int TPB = 1024;            // 16 waves
constexpr int CHUNKS = 256;          // tid>>2
constexpr int TILE = 4096;           // sources per LDS tile (64 KB float4)
constexpr int TILES = N_SRC / TILE;  // 4
constexpr int IPT = TILE / CHUNKS / 2;  // 8 source-pairs per tile per thread

__global__ void zero_out(float* __restrict__ out) {
    if (threadIdx.x == 0) out[0] = 0.0f;  // d_out poisoned 0xAA each launch
}

// (t & mask_v) | row_s  — mask forced to VGPR, uniform row rides the SGPR slot
__device__ __forceinline__ float embed_ao(float t, unsigned mask_v, unsigned row_s) {
    float r;
    asm("v_and_or_b32 %0, %1, %2, %3"
        : "=v"(r) : "v"(t), "v"(mask_v), "s"(row_s));
    return r;
}
// best = min(best, e0, e1) in one instruction (inputs never NaN here)
__device__ __forceinline__ void min3(float& b, float e0, float e1) {
    asm("v_min3_f32 %0, %1, %2, %3"
        : "=v"(b) : "v"(b), "v"(e0), "v"(e1));
}

__global__ __launch_bounds__(TPB, 8) void nn6(const float* __restrict__ src,
                                              const float* __restrict__ tar,
                                              float* __restrict__ out) {
    __shared__ float4 tile[TILE];  // 64 KB; reused as (fv, fj) in the tail

    const int tid   = threadIdx.x;
    const int g     = tid & 3;
    const int chunk = tid >> 2;    // 0..255
    const int tbase = blockIdx.x * 32;

    // 8 targets/thread, premultiplied by -2 so ||s||^2 folds into the fma chain
    float txm2[8], tym2[8], tzm2[8], best[8];
#pragma unroll
    for (int k = 0; k < 8; ++k) {
        int T = tbase + g + 4 * k;
        txm2[k] = -2.0f * tar[3 * T + 0];
        tym2[k] = -2.0f * tar[3 * T + 1];
        tzm2[k] = -2.0f * tar[3 * T + 2];
        best[k] = INFINITY;
    }

    unsigned mask_v = 0xFFFFFFC0u;  // lives in a VGPR for v_and_or_b32

    for (int tl = 0; tl < TILES; ++tl) {
        // ---- stage tile: 4096 sources as (x,y,z,||s||^2)
#pragma unroll
        for (int r = 0; r < TILE / TPB; ++r) {
            int p  = tid + r * TPB;
            int j3 = 3 * (tl * TILE + p);
            float x = src[j3 + 0], y = src[j3 + 1], z = src[j3 + 2];
            tile[p] = make_float4(x, y, z, fmaf(x, x, fmaf(y, y, z * z)));
        }
        __syncthreads();

        // ---- scan: v(j) = ||s||^2 - 2 t.s ; fully unrolled -> imm ds offsets
#pragma unroll
        for (int i = 0; i < IPT; ++i) {
            float4 s0 = tile[(2 * i + 0) * CHUNKS + chunk];
            float4 s1 = tile[(2 * i + 1) * CHUNKS + chunk];
            unsigned row0 = (unsigned)(tl * 2 * IPT + 2 * i + 0);  // uniform
            unsigned row1 = (unsigned)(tl * 2 * IPT + 2 * i + 1);  // uniform
#pragma unroll
            for (int k = 0; k < 8; ++k) {
                float t0 = fmaf(s0.z, tzm2[k], s0.w);
                t0 = fmaf(s0.y, tym2[k], t0);
                t0 = fmaf(s0.x, txm2[k], t0);
                float t1 = fmaf(s1.z, tzm2[k], s1.w);
                t1 = fmaf(s1.y, tym2[k], t1);
                t1 = fmaf(s1.x, txm2[k], t1);
                float e0 = embed_ao(t0, mask_v, row0);
                float e1 = embed_ao(t1, mask_v, row1);
                min3(best[k], e0, e1);
            }
        }
        __syncthreads();
    }

    // ---- tail: resolve indices, merge 256 chunks per target, loss, atomic
    float* fv = (float*)tile;            // [32][256] values  (32 KB)
    int*   fj = (int*)tile + 32 * 256;   // [32][256] indices (32 KB)
#pragma unroll
    for (int k = 0; k < 8; ++k) {
        unsigned b = __float_as_uint(best[k]);
        int j  = (int)((b & 63u) * CHUNKS + chunk);  // j = row*256 + chunk
        int lt = g + 4 * k;
        fv[lt * CHUNKS + chunk] = __uint_as_float(b & 0xFFFFFFC0u);
        fj[lt * CHUNKS + chunk] = j;
    }
    __syncthreads();

    const int tprime = tid >> 5;   // 0..31: target this half-wave reduces
    const int sub    = tid & 31;
    float bv = fv[tprime * CHUNKS + sub];
    int   bj = fj[tprime * CHUNKS + sub];
#pragma unroll
    for (int m = 1; m < 8; ++m) {
        float v = fv[tprime * CHUNKS + sub + 32 * m];
        int   j = fj[tprime * CHUNKS + sub + 32 * m];
        if (v < bv) { bv = v; bj = j; }
    }
#pragma unroll
    for (int s = 16; s >= 1; s >>= 1) {   // xor<32 stays in the half-wave
        float vv = __shfl_xor(bv, s, 64);
        int   jj = __shfl_xor(bj, s, 64);
        if (vv < bv) { bv = vv; bj = jj; }
    }
    __syncthreads();  // done reading fv/fj; safe to reuse

    if (sub == 0) {
        int tt = tbase + tprime;
        // exact loss term from the winning index (reference formula)
        float dx = src[3 * bj + 0] - tar[3 * tt + 0];
        float dy = src[3 * bj + 1] - tar[3 * tt + 1];
        float dz = src[3 * bj + 2] - tar[3 * tt + 2];
        fv[tprime] = 0.5f * fmaf(dx, dx, fmaf(dy, dy, dz * dz));
    }
    __syncthreads();
    if (tid == 0) {
        float ssum = 0.0f;
#pragma unroll
        for (int i = 0; i < 32; ++i) ssum += fv[i];
        atomicAdd(out, ssum);  // device-scope, cross-XCD safe
    }
}

extern "C" void kernel_launch(void* const* d_in, const int* in_sizes, int n_in,
                              void* d_out, int out_size, void* d_ws, size_t ws_size,
                              hipStream_t stream) {
    const float* src = (const float*)d_in[0];  // src_V [N,3] fp32
    const float* tar = (const float*)d_in[1];  // tar_V [M,3] fp32
    float* out = (float*)d_out;                // scalar loss fp32
    (void)d_ws; (void)ws_size;

    zero_out<<<1, 64, 0, stream>>>(out);
    nn6<<<BLOCKS, TPB, 0, stream>>>(src, tar, out);
}